// Round 1
// baseline (213.663 us; speedup 1.0000x reference)
//
#include <hip/hip_runtime.h>
#include <math.h>

// Problem constants
#define B 2
#define N 8192            // points per batch (both preds and gts)
#define PTS_STRIDE (N*3)  // floats per batch
#define VOXEL 0.1f

// ws layout (floats):
//  [0..15]   : gmin[arr][b][3]  (arr0=preds, arr1=gts), padded
//  [16 .. 16+32768)         : rawmin[dir][b][n]  (dir0: preds-side d1, dir1: gts-side d2)
//  [16+32768 .. 16+65536)   : voxmin[dir][b][n]
#define WS_GMIN   0
#define WS_MINS   16
#define MINS_TOTAL 65536   // 4 * 16384

#define TX 4          // x-points per thread
#define BLK 256       // threads per block
#define CHUNK 256     // y points per block (per y-split)

__global__ void prep_kernel(const float* __restrict__ preds,
                            const float* __restrict__ gts,
                            float* __restrict__ ws) {
    const int arr = blockIdx.x >> 1;
    const int b   = blockIdx.x & 1;
    const float* base = (arr ? gts : preds) + b * PTS_STRIDE;

    float m0 = INFINITY, m1 = INFINITY, m2 = INFINITY;
    for (int i = threadIdx.x; i < N; i += BLK) {
        float v0 = base[i*3+0], v1 = base[i*3+1], v2 = base[i*3+2];
        v0 = (v0 != v0) ? INFINITY : v0;   // NaN -> inf (matches masked_fill)
        v1 = (v1 != v1) ? INFINITY : v1;
        v2 = (v2 != v2) ? INFINITY : v2;
        m0 = fminf(m0, v0); m1 = fminf(m1, v1); m2 = fminf(m2, v2);
    }
    // wave (64-lane) reduce
    for (int off = 32; off; off >>= 1) {
        m0 = fminf(m0, __shfl_down(m0, off));
        m1 = fminf(m1, __shfl_down(m1, off));
        m2 = fminf(m2, __shfl_down(m2, off));
    }
    __shared__ float sm[4][3];
    const int wave = threadIdx.x >> 6, lane = threadIdx.x & 63;
    if (lane == 0) { sm[wave][0] = m0; sm[wave][1] = m1; sm[wave][2] = m2; }
    __syncthreads();
    if (threadIdx.x == 0) {
        float a0 = fminf(fminf(sm[0][0], sm[1][0]), fminf(sm[2][0], sm[3][0]));
        float a1 = fminf(fminf(sm[0][1], sm[1][1]), fminf(sm[2][1], sm[3][1]));
        float a2 = fminf(fminf(sm[0][2], sm[1][2]), fminf(sm[2][2], sm[3][2]));
        const int gi = WS_GMIN + (arr*2 + b)*3;
        ws[gi+0] = a0; ws[gi+1] = a1; ws[gi+2] = a2;
    }
    // init per-point min arrays (each of the 4 blocks inits a quarter)
    float* mins = ws + WS_MINS;
    const int quarter = MINS_TOTAL / 4;
    for (int i = threadIdx.x; i < quarter; i += BLK)
        mins[blockIdx.x * quarter + i] = INFINITY;
}

__device__ __forceinline__ float voxq(float v, float g) {
    return (float)(int)((v - g) / VOXEL);   // trunc like .astype(int32)
}

__global__ void __launch_bounds__(BLK)
chamfer_kernel(const float* __restrict__ preds,
               const float* __restrict__ gts,
               float* __restrict__ ws) {
    const int tid = threadIdx.x;
    const int dir = blockIdx.z & 1;      // 0: X=preds vs Y=gts ; 1: swapped
    const int b   = blockIdx.z >> 1;
    const float* X = dir ? gts : preds;
    const float* Y = dir ? preds : gts;
    const int arrX = dir, arrY = 1 - dir;

    const float gx0 = ws[WS_GMIN + (arrX*2+b)*3+0];
    const float gx1 = ws[WS_GMIN + (arrX*2+b)*3+1];
    const float gx2 = ws[WS_GMIN + (arrX*2+b)*3+2];
    const float gy0 = ws[WS_GMIN + (arrY*2+b)*3+0];
    const float gy1 = ws[WS_GMIN + (arrY*2+b)*3+1];
    const float gy2 = ws[WS_GMIN + (arrY*2+b)*3+2];

    __shared__ float4 ldsR[CHUNK];
    __shared__ float4 ldsV[CHUNK];

    // stage y chunk (raw + voxelized) into LDS
    const float* Yb = Y + b * PTS_STRIDE;
    const int ys = blockIdx.y * CHUNK;
    for (int i = tid; i < CHUNK; i += BLK) {
        const float y0 = Yb[(ys+i)*3+0];
        const float y1 = Yb[(ys+i)*3+1];
        const float y2 = Yb[(ys+i)*3+2];
        ldsR[i] = make_float4(y0, y1, y2, 0.0f);
        ldsV[i] = make_float4(voxq(y0, gy0), voxq(y1, gy1), voxq(y2, gy2), 0.0f);
    }

    // per-thread x points (registers)
    const float* Xb = X + b * PTS_STRIDE;
    const int x0 = blockIdx.x * (BLK * TX);
    float xr[TX][3], xv[TX][3], mr[TX], mv[TX];
#pragma unroll
    for (int t = 0; t < TX; ++t) {
        const int xi = x0 + t*BLK + tid;
        xr[t][0] = Xb[xi*3+0]; xr[t][1] = Xb[xi*3+1]; xr[t][2] = Xb[xi*3+2];
        xv[t][0] = voxq(xr[t][0], gx0);
        xv[t][1] = voxq(xr[t][1], gx1);
        xv[t][2] = voxq(xr[t][2], gx2);
        mr[t] = INFINITY; mv[t] = INFINITY;
    }
    __syncthreads();

    for (int j = 0; j < CHUNK; ++j) {
        const float4 yr = ldsR[j];
        const float4 yv = ldsV[j];
#pragma unroll
        for (int t = 0; t < TX; ++t) {
            float dx = xr[t][0] - yr.x;
            float dy = xr[t][1] - yr.y;
            float dz = xr[t][2] - yr.z;
            float dr = fmaf(dx, dx, fmaf(dy, dy, dz*dz));
            mr[t] = fminf(mr[t], dr);
            dx = xv[t][0] - yv.x;
            dy = xv[t][1] - yv.y;
            dz = xv[t][2] - yv.z;
            float dv = fmaf(dx, dx, fmaf(dy, dy, dz*dz));
            mv[t] = fminf(mv[t], dv);
        }
    }

    // combine across y-splits: atomicMin on uint bits (all values >= 0)
    unsigned int* rawmin = (unsigned int*)(ws + WS_MINS);
    unsigned int* voxmin = rawmin + 32768;
#pragma unroll
    for (int t = 0; t < TX; ++t) {
        const int xi = x0 + t*BLK + tid;
        const int idx = dir * (B*N) + b * N + xi;
        atomicMin(&rawmin[idx], __float_as_uint(mr[t]));
        atomicMin(&voxmin[idx], __float_as_uint(mv[t]));
    }
}

__global__ void finalize_kernel(const float* __restrict__ ws,
                                float* __restrict__ out) {
    const float* mins = ws + WS_MINS;
    float s = 0.0f;
    for (int i = threadIdx.x; i < MINS_TOTAL; i += BLK)
        s += mins[i];
    for (int off = 32; off; off >>= 1)
        s += __shfl_down(s, off);
    __shared__ float sm[4];
    const int wave = threadIdx.x >> 6, lane = threadIdx.x & 63;
    if (lane == 0) sm[wave] = s;
    __syncthreads();
    if (threadIdx.x == 0) {
        const float total = sm[0] + sm[1] + sm[2] + sm[3];
        // d1.mean()+d2.mean() (raw) + same (voxel); all means are sum/16384
        out[0] = total * (1.0f / 16384.0f);
    }
}

extern "C" void kernel_launch(void* const* d_in, const int* in_sizes, int n_in,
                              void* d_out, int out_size, void* d_ws, size_t ws_size,
                              hipStream_t stream) {
    const float* preds = (const float*)d_in[0];
    const float* gts   = (const float*)d_in[1];
    float* ws  = (float*)d_ws;
    float* out = (float*)d_out;

    prep_kernel<<<dim3(4), dim3(BLK), 0, stream>>>(preds, gts, ws);
    // grid: 8 x-tiles (1024 x each) × 32 y-splits (256 y each) × (2 dirs × 2 batches)
    chamfer_kernel<<<dim3(N/(BLK*TX), N/CHUNK, 4), dim3(BLK), 0, stream>>>(preds, gts, ws);
    finalize_kernel<<<dim3(1), dim3(BLK), 0, stream>>>(ws, out);
}

// Round 2
// 128.259 us; speedup vs baseline: 1.6659x; 1.6659x over previous
//
#include <hip/hip_runtime.h>
#include <math.h>

// Problem constants
#define B 2
#define N 8192            // points per batch (both preds and gts)
#define PTS_STRIDE (N*3)  // floats per batch
#define VOXEL 0.1f

// ws layout (floats):
//  [0..15]   : gmin[arr][b][3]  (arr0=preds, arr1=gts), padded
//  [16 .. 16+32768)         : rawmin[dir][b][n]
//  [16+32768 .. 16+65536)   : voxmin[dir][b][n]
#define WS_GMIN   0
#define WS_MINS   16
#define MINS_TOTAL 65536   // 4 * 16384

#define TX 4          // x-points per thread
#define BLK 256       // threads per block (chamfer)
#define CHUNK 256     // y points per block (per y-split)
#define PBLK 1024     // threads per block (prep/finalize)

__global__ void __launch_bounds__(PBLK)
prep_kernel(const float* __restrict__ preds,
            const float* __restrict__ gts,
            float* __restrict__ ws) {
    const int arr = blockIdx.x >> 1;
    const int b   = blockIdx.x & 1;
    const float* base = (arr ? gts : preds) + b * PTS_STRIDE;

    float m0 = INFINITY, m1 = INFINITY, m2 = INFINITY;
    for (int i = threadIdx.x; i < N; i += PBLK) {
        float v0 = base[i*3+0], v1 = base[i*3+1], v2 = base[i*3+2];
        v0 = (v0 != v0) ? INFINITY : v0;   // NaN -> inf (matches masked_fill)
        v1 = (v1 != v1) ? INFINITY : v1;
        v2 = (v2 != v2) ? INFINITY : v2;
        m0 = fminf(m0, v0); m1 = fminf(m1, v1); m2 = fminf(m2, v2);
    }
    for (int off = 32; off; off >>= 1) {
        m0 = fminf(m0, __shfl_down(m0, off));
        m1 = fminf(m1, __shfl_down(m1, off));
        m2 = fminf(m2, __shfl_down(m2, off));
    }
    __shared__ float sm[16][3];
    const int wave = threadIdx.x >> 6, lane = threadIdx.x & 63;
    if (lane == 0) { sm[wave][0] = m0; sm[wave][1] = m1; sm[wave][2] = m2; }
    __syncthreads();
    if (threadIdx.x == 0) {
        float a0 = sm[0][0], a1 = sm[0][1], a2 = sm[0][2];
        for (int w = 1; w < 16; ++w) {
            a0 = fminf(a0, sm[w][0]);
            a1 = fminf(a1, sm[w][1]);
            a2 = fminf(a2, sm[w][2]);
        }
        const int gi = WS_GMIN + (arr*2 + b)*3;
        ws[gi+0] = a0; ws[gi+1] = a1; ws[gi+2] = a2;
    }
    // init per-point min arrays (each of the 4 blocks inits a quarter)
    float* mins = ws + WS_MINS;
    const int quarter = MINS_TOTAL / 4;
    for (int i = threadIdx.x; i < quarter; i += PBLK)
        mins[blockIdx.x * quarter + i] = INFINITY;
}

__device__ __forceinline__ float voxq(float v, float g) {
    return (float)(int)((v - g) / VOXEL);   // trunc like .astype(int32)
}

__global__ void __launch_bounds__(BLK, 4)
chamfer_kernel(const float* __restrict__ preds,
               const float* __restrict__ gts,
               float* __restrict__ ws) {
    const int tid = threadIdx.x;
    const int dir = blockIdx.z & 1;      // 0: X=preds vs Y=gts ; 1: swapped
    const int b   = blockIdx.z >> 1;
    const float* X = dir ? gts : preds;
    const float* Y = dir ? preds : gts;
    const int arrX = dir, arrY = 1 - dir;

    const float gx0 = ws[WS_GMIN + (arrX*2+b)*3+0];
    const float gx1 = ws[WS_GMIN + (arrX*2+b)*3+1];
    const float gx2 = ws[WS_GMIN + (arrX*2+b)*3+2];
    const float gy0 = ws[WS_GMIN + (arrY*2+b)*3+0];
    const float gy1 = ws[WS_GMIN + (arrY*2+b)*3+1];
    const float gy2 = ws[WS_GMIN + (arrY*2+b)*3+2];

    __shared__ float4 ldsR[CHUNK];
    __shared__ float4 ldsV[CHUNK];

    // stage y chunk (raw + voxelized) into LDS
    const float* Yb = Y + b * PTS_STRIDE;
    const int ys = blockIdx.y * CHUNK;
    for (int i = tid; i < CHUNK; i += BLK) {
        const float y0 = Yb[(ys+i)*3+0];
        const float y1 = Yb[(ys+i)*3+1];
        const float y2 = Yb[(ys+i)*3+2];
        ldsR[i] = make_float4(y0, y1, y2, 0.0f);
        ldsV[i] = make_float4(voxq(y0, gy0), voxq(y1, gy1), voxq(y2, gy2), 0.0f);
    }

    // per-thread x points (registers) — launch_bounds(256,4) leaves 128 VGPRs
    const float* Xb = X + b * PTS_STRIDE;
    const int x0 = blockIdx.x * (BLK * TX);
    float xr[TX][3], xv[TX][3], mr[TX], mv[TX];
#pragma unroll
    for (int t = 0; t < TX; ++t) {
        const int xi = x0 + t*BLK + tid;
        xr[t][0] = Xb[xi*3+0]; xr[t][1] = Xb[xi*3+1]; xr[t][2] = Xb[xi*3+2];
        xv[t][0] = voxq(xr[t][0], gx0);
        xv[t][1] = voxq(xr[t][1], gx1);
        xv[t][2] = voxq(xr[t][2], gx2);
        mr[t] = INFINITY; mv[t] = INFINITY;
    }
    __syncthreads();

#pragma unroll 4
    for (int j = 0; j < CHUNK; ++j) {
        const float4 yr = ldsR[j];
        const float4 yv = ldsV[j];
#pragma unroll
        for (int t = 0; t < TX; ++t) {
            float dx = xr[t][0] - yr.x;
            float dy = xr[t][1] - yr.y;
            float dz = xr[t][2] - yr.z;
            float dr = fmaf(dx, dx, fmaf(dy, dy, dz*dz));
            mr[t] = fminf(mr[t], dr);
            dx = xv[t][0] - yv.x;
            dy = xv[t][1] - yv.y;
            dz = xv[t][2] - yv.z;
            float dv = fmaf(dx, dx, fmaf(dy, dy, dz*dz));
            mv[t] = fminf(mv[t], dv);
        }
    }

    // combine across y-splits: atomicMin on uint bits (all values >= 0)
    unsigned int* rawmin = (unsigned int*)(ws + WS_MINS);
    unsigned int* voxmin = rawmin + 32768;
#pragma unroll
    for (int t = 0; t < TX; ++t) {
        const int xi = x0 + t*BLK + tid;
        const int idx = dir * (B*N) + b * N + xi;
        atomicMin(&rawmin[idx], __float_as_uint(mr[t]));
        atomicMin(&voxmin[idx], __float_as_uint(mv[t]));
    }
}

__global__ void __launch_bounds__(PBLK)
finalize_kernel(const float* __restrict__ ws,
                float* __restrict__ out) {
    const float4* m4 = (const float4*)(ws + WS_MINS);  // 64B-aligned offset
    float s = 0.0f;
#pragma unroll 4
    for (int i = threadIdx.x; i < MINS_TOTAL/4; i += PBLK) {
        const float4 v = m4[i];
        s += (v.x + v.y) + (v.z + v.w);
    }
    for (int off = 32; off; off >>= 1)
        s += __shfl_down(s, off);
    __shared__ float sm[16];
    const int wave = threadIdx.x >> 6, lane = threadIdx.x & 63;
    if (lane == 0) sm[wave] = s;
    __syncthreads();
    if (threadIdx.x == 0) {
        float total = 0.0f;
        for (int w = 0; w < 16; ++w) total += sm[w];
        // d1.mean()+d2.mean() (raw) + same (voxel); all means are sum/16384
        out[0] = total * (1.0f / 16384.0f);
    }
}

extern "C" void kernel_launch(void* const* d_in, const int* in_sizes, int n_in,
                              void* d_out, int out_size, void* d_ws, size_t ws_size,
                              hipStream_t stream) {
    const float* preds = (const float*)d_in[0];
    const float* gts   = (const float*)d_in[1];
    float* ws  = (float*)d_ws;
    float* out = (float*)d_out;

    prep_kernel<<<dim3(4), dim3(PBLK), 0, stream>>>(preds, gts, ws);
    // grid: 8 x-tiles (1024 x each) × 32 y-splits (256 y each) × (2 dirs × 2 batches)
    chamfer_kernel<<<dim3(N/(BLK*TX), N/CHUNK, 4), dim3(BLK), 0, stream>>>(preds, gts, ws);
    finalize_kernel<<<dim3(1), dim3(PBLK), 0, stream>>>(ws, out);
}

// Round 3
// 108.107 us; speedup vs baseline: 1.9764x; 1.1864x over previous
//
#include <hip/hip_runtime.h>
#include <math.h>

// Problem constants
#define B 2
#define N 8192            // points per batch (both preds and gts)
#define PTS_STRIDE (N*3)  // floats per batch
#define VOXEL 0.1f

// ws layout (floats):
//  [0..15]                  : gmin[arr][b][3]  (arr0=preds, arr1=gts)
//  [16 .. 16+65536)         : per-point mins: rawmin[dir][b][n] (32768) then voxmin (32768)
//  [WS_PACK ..)             : packed float4 per (arr,b): raw4[N] then vox4[N]
//                             pack(p) = (p0,p1,p2,|p|^2)
#define WS_GMIN   0
#define WS_MINS   16
#define MINS_TOTAL 65536   // 4 * 16384
#define WS_PACK   (WS_MINS + MINS_TOTAL)
#define WS_NEEDED_FLOATS (WS_PACK + 4 /*arr,b*/ * N * 8 /*raw4+vox4*/)

#define TX 4          // x-points per thread
#define BLK 256       // threads per block (chamfer)
#define CHUNK 256     // y points per block (per y-split)
#define PBLK 1024     // threads per block (prep/finalize)

__device__ __forceinline__ float voxq(float v, float g) {
    return (float)(int)((v - g) / VOXEL);   // trunc like .astype(int32)
}

__global__ void __launch_bounds__(PBLK)
prep_kernel(const float* __restrict__ preds,
            const float* __restrict__ gts,
            float* __restrict__ ws, int write_pack) {
    const int arr = blockIdx.x >> 1;
    const int b   = blockIdx.x & 1;
    const float* base = (arr ? gts : preds) + b * PTS_STRIDE;

    float m0 = INFINITY, m1 = INFINITY, m2 = INFINITY;
    for (int i = threadIdx.x; i < N; i += PBLK) {
        float v0 = base[i*3+0], v1 = base[i*3+1], v2 = base[i*3+2];
        v0 = (v0 != v0) ? INFINITY : v0;   // NaN -> inf (matches masked_fill)
        v1 = (v1 != v1) ? INFINITY : v1;
        v2 = (v2 != v2) ? INFINITY : v2;
        m0 = fminf(m0, v0); m1 = fminf(m1, v1); m2 = fminf(m2, v2);
    }
    for (int off = 32; off; off >>= 1) {
        m0 = fminf(m0, __shfl_down(m0, off));
        m1 = fminf(m1, __shfl_down(m1, off));
        m2 = fminf(m2, __shfl_down(m2, off));
    }
    __shared__ float sm[16][3];
    __shared__ float g[3];
    const int wave = threadIdx.x >> 6, lane = threadIdx.x & 63;
    if (lane == 0) { sm[wave][0] = m0; sm[wave][1] = m1; sm[wave][2] = m2; }
    __syncthreads();
    if (threadIdx.x == 0) {
        float a0 = sm[0][0], a1 = sm[0][1], a2 = sm[0][2];
        for (int w = 1; w < 16; ++w) {
            a0 = fminf(a0, sm[w][0]);
            a1 = fminf(a1, sm[w][1]);
            a2 = fminf(a2, sm[w][2]);
        }
        const int gi = WS_GMIN + (arr*2 + b)*3;
        ws[gi+0] = a0; ws[gi+1] = a1; ws[gi+2] = a2;
        g[0] = a0; g[1] = a1; g[2] = a2;
    }
    __syncthreads();

    if (write_pack) {
        const float g0 = g[0], g1 = g[1], g2 = g[2];
        float4* raw4 = (float4*)(ws + WS_PACK + (arr*2+b)*N*8);
        float4* vox4 = raw4 + N;
        for (int i = threadIdx.x; i < N; i += PBLK) {
            const float p0 = base[i*3+0], p1 = base[i*3+1], p2 = base[i*3+2];
            raw4[i] = make_float4(p0, p1, p2,
                                  fmaf(p0,p0, fmaf(p1,p1, p2*p2)));
            const float v0 = voxq(p0, g0), v1 = voxq(p1, g1), v2 = voxq(p2, g2);
            vox4[i] = make_float4(v0, v1, v2,
                                  fmaf(v0,v0, fmaf(v1,v1, v2*v2)));
        }
    }

    // init per-point min arrays (each of the 4 blocks inits a quarter)
    float* mins = ws + WS_MINS;
    const int quarter = MINS_TOTAL / 4;
    for (int i = threadIdx.x; i < quarter; i += PBLK)
        mins[blockIdx.x * quarter + i] = INFINITY;
}

// Fast path: dot-product form on prepacked (p0,p1,p2,|p|^2) float4 arrays.
// d(x,y) = |y|^2 - 2 x.y + |x|^2 ; min over y of (|y|^2 - 2 x.y), add |x|^2 after.
__global__ void __launch_bounds__(BLK, 4)
chamfer_kernel(float* __restrict__ ws) {
    const int tid = threadIdx.x;
    const int dir = blockIdx.z & 1;      // 0: X=preds vs Y=gts ; 1: swapped
    const int b   = blockIdx.z >> 1;
    const int arrX = dir, arrY = 1 - dir;

    const float4* Xr = (const float4*)(ws + WS_PACK + (arrX*2+b)*N*8);
    const float4* Xv = Xr + N;
    const float4* Yr = (const float4*)(ws + WS_PACK + (arrY*2+b)*N*8);
    const float4* Yv = Yr + N;

    __shared__ float4 ldsR[CHUNK];
    __shared__ float4 ldsV[CHUNK];

    const int ys = blockIdx.y * CHUNK;
    for (int i = tid; i < CHUNK; i += BLK) {
        ldsR[i] = Yr[ys + i];
        ldsV[i] = Yv[ys + i];
    }

    const int x0 = blockIdx.x * (BLK * TX);
    float ar[TX][3], av[TX][3], xxr[TX], xxv[TX], mr[TX], mv[TX];
#pragma unroll
    for (int t = 0; t < TX; ++t) {
        const int xi = x0 + t*BLK + tid;
        const float4 r = Xr[xi];
        ar[t][0] = -2.0f*r.x; ar[t][1] = -2.0f*r.y; ar[t][2] = -2.0f*r.z;
        xxr[t] = r.w;
        const float4 v = Xv[xi];
        av[t][0] = -2.0f*v.x; av[t][1] = -2.0f*v.y; av[t][2] = -2.0f*v.z;
        xxv[t] = v.w;
        mr[t] = INFINITY; mv[t] = INFINITY;
    }
    __syncthreads();

#pragma unroll 4
    for (int j = 0; j < CHUNK; ++j) {
        const float4 yr = ldsR[j];
        const float4 yv = ldsV[j];
#pragma unroll
        for (int t = 0; t < TX; ++t) {
            const float dr = fmaf(ar[t][0], yr.x,
                             fmaf(ar[t][1], yr.y,
                             fmaf(ar[t][2], yr.z, yr.w)));
            mr[t] = fminf(mr[t], dr);
            const float dv = fmaf(av[t][0], yv.x,
                             fmaf(av[t][1], yv.y,
                             fmaf(av[t][2], yv.z, yv.w)));
            mv[t] = fminf(mv[t], dv);
        }
    }

    // combine across y-splits: atomicMin on uint bits (all values >= ~0;
    // tiny fp-negative mins map to huge uints -> bounded ~1e-6 error, ok)
    unsigned int* rawmin = (unsigned int*)(ws + WS_MINS);
    unsigned int* voxmin = rawmin + 32768;
#pragma unroll
    for (int t = 0; t < TX; ++t) {
        const int xi = x0 + t*BLK + tid;
        const int idx = dir * (B*N) + b * N + xi;
        atomicMin(&rawmin[idx], __float_as_uint(mr[t] + xxr[t]));
        atomicMin(&voxmin[idx], __float_as_uint(mv[t] + xxv[t]));
    }
}

// Fallback (R2 kernel): used only if ws_size can't hold the packed arrays.
__global__ void __launch_bounds__(BLK, 4)
chamfer_fb_kernel(const float* __restrict__ preds,
                  const float* __restrict__ gts,
                  float* __restrict__ ws) {
    const int tid = threadIdx.x;
    const int dir = blockIdx.z & 1;
    const int b   = blockIdx.z >> 1;
    const float* X = dir ? gts : preds;
    const float* Y = dir ? preds : gts;
    const int arrX = dir, arrY = 1 - dir;

    const float gx0 = ws[WS_GMIN + (arrX*2+b)*3+0];
    const float gx1 = ws[WS_GMIN + (arrX*2+b)*3+1];
    const float gx2 = ws[WS_GMIN + (arrX*2+b)*3+2];
    const float gy0 = ws[WS_GMIN + (arrY*2+b)*3+0];
    const float gy1 = ws[WS_GMIN + (arrY*2+b)*3+1];
    const float gy2 = ws[WS_GMIN + (arrY*2+b)*3+2];

    __shared__ float4 ldsR[CHUNK];
    __shared__ float4 ldsV[CHUNK];

    const float* Yb = Y + b * PTS_STRIDE;
    const int ys = blockIdx.y * CHUNK;
    for (int i = tid; i < CHUNK; i += BLK) {
        const float y0 = Yb[(ys+i)*3+0];
        const float y1 = Yb[(ys+i)*3+1];
        const float y2 = Yb[(ys+i)*3+2];
        ldsR[i] = make_float4(y0, y1, y2, 0.0f);
        ldsV[i] = make_float4(voxq(y0, gy0), voxq(y1, gy1), voxq(y2, gy2), 0.0f);
    }

    const float* Xb = X + b * PTS_STRIDE;
    const int x0 = blockIdx.x * (BLK * TX);
    float xr[TX][3], xv[TX][3], mr[TX], mv[TX];
#pragma unroll
    for (int t = 0; t < TX; ++t) {
        const int xi = x0 + t*BLK + tid;
        xr[t][0] = Xb[xi*3+0]; xr[t][1] = Xb[xi*3+1]; xr[t][2] = Xb[xi*3+2];
        xv[t][0] = voxq(xr[t][0], gx0);
        xv[t][1] = voxq(xr[t][1], gx1);
        xv[t][2] = voxq(xr[t][2], gx2);
        mr[t] = INFINITY; mv[t] = INFINITY;
    }
    __syncthreads();

#pragma unroll 4
    for (int j = 0; j < CHUNK; ++j) {
        const float4 yr = ldsR[j];
        const float4 yv = ldsV[j];
#pragma unroll
        for (int t = 0; t < TX; ++t) {
            float dx = xr[t][0] - yr.x;
            float dy = xr[t][1] - yr.y;
            float dz = xr[t][2] - yr.z;
            float dr = fmaf(dx, dx, fmaf(dy, dy, dz*dz));
            mr[t] = fminf(mr[t], dr);
            dx = xv[t][0] - yv.x;
            dy = xv[t][1] - yv.y;
            dz = xv[t][2] - yv.z;
            float dv = fmaf(dx, dx, fmaf(dy, dy, dz*dz));
            mv[t] = fminf(mv[t], dv);
        }
    }

    unsigned int* rawmin = (unsigned int*)(ws + WS_MINS);
    unsigned int* voxmin = rawmin + 32768;
#pragma unroll
    for (int t = 0; t < TX; ++t) {
        const int xi = x0 + t*BLK + tid;
        const int idx = dir * (B*N) + b * N + xi;
        atomicMin(&rawmin[idx], __float_as_uint(mr[t]));
        atomicMin(&voxmin[idx], __float_as_uint(mv[t]));
    }
}

__global__ void __launch_bounds__(PBLK)
finalize_kernel(const float* __restrict__ ws,
                float* __restrict__ out) {
    const float4* m4 = (const float4*)(ws + WS_MINS);
    float s = 0.0f;
#pragma unroll 4
    for (int i = threadIdx.x; i < MINS_TOTAL/4; i += PBLK) {
        const float4 v = m4[i];
        s += (v.x + v.y) + (v.z + v.w);
    }
    for (int off = 32; off; off >>= 1)
        s += __shfl_down(s, off);
    __shared__ float sm[16];
    const int wave = threadIdx.x >> 6, lane = threadIdx.x & 63;
    if (lane == 0) sm[wave] = s;
    __syncthreads();
    if (threadIdx.x == 0) {
        float total = 0.0f;
        for (int w = 0; w < 16; ++w) total += sm[w];
        out[0] = total * (1.0f / 16384.0f);
    }
}

extern "C" void kernel_launch(void* const* d_in, const int* in_sizes, int n_in,
                              void* d_out, int out_size, void* d_ws, size_t ws_size,
                              hipStream_t stream) {
    const float* preds = (const float*)d_in[0];
    const float* gts   = (const float*)d_in[1];
    float* ws  = (float*)d_ws;
    float* out = (float*)d_out;

    const int pack = (ws_size >= (size_t)WS_NEEDED_FLOATS * sizeof(float)) ? 1 : 0;

    prep_kernel<<<dim3(4), dim3(PBLK), 0, stream>>>(preds, gts, ws, pack);
    if (pack) {
        chamfer_kernel<<<dim3(N/(BLK*TX), N/CHUNK, 4), dim3(BLK), 0, stream>>>(ws);
    } else {
        chamfer_fb_kernel<<<dim3(N/(BLK*TX), N/CHUNK, 4), dim3(BLK), 0, stream>>>(preds, gts, ws);
    }
    finalize_kernel<<<dim3(1), dim3(PBLK), 0, stream>>>(ws, out);
}